// Round 5
// baseline (208.427 us; speedup 1.0000x reference)
//
#include <hip/hip_runtime.h>
#include <hip/hip_cooperative_groups.h>

namespace cg = cooperative_groups;

// Problem constants (fixed by reference)
#define D_DIRS 1024
#define P_PTS  256
#define R_RANK 64
#define K_SUB  1024

typedef float v4f __attribute__((ext_vector_type(4)));

// Workspace layout in floats:
//   a[D][R]      @ 0        (65536)
//   b[D][R]      @ 65536    (65536)
//   Msum[64][64] @ 131072   (4096)  -- zeroed by block 0 in phase 1, ordered
//                                      by grid.sync before phase-2 atomics.
#define WS_A 0
#define WS_B (D_DIRS * R_RANK)
#define WS_MSUM (2 * D_DIRS * R_RANK)
#define NB_B 32
#define DCHUNK (D_DIRS / NB_B) // 32

__device__ __forceinline__ v4f ntload(const v4f* __restrict__ p) {
    return __builtin_nontemporal_load(p);
}

__device__ __forceinline__ v4f shfl_xor_v4(v4f v, int m) {
    v4f r;
    r.x = __shfl_xor(v.x, m);
    r.y = __shfl_xor(v.y, m);
    r.z = __shfl_xor(v.z, m);
    r.w = __shfl_xor(v.w, m);
    return r;
}

// ---------------------------------------------------------------------------
// R11: single cooperative kernel fusing the R0-proven three-kernel chain.
// k1 evidence ledger (closed): nt streaming = 33 us / 4.1 TB/s (best of 8
// variants over 2 sessions). Cached-path reads capped ~3.0 TB/s in BOTH a
// compiler-collapsed (R2) and an asm-pipelined (R4) structure -- LLC
// allocation against the harness's 256 MB dirty fill loses to pure HBM nt
// streaming. Occupancy doubling neutral (R7). De-atomicized M regressed
// +11.5 us (R9). What remains: ~33 us of k2+k3+two launch boundaries for
// ~<15 us of actual work -> fuse with grid.sync, eliminate the boundaries.
//
// Phase 1 (all 256 blocks, 512 thr): wave-private p-reduction, nt loads,
//   8-load chunks 2-deep, shfl_xor 8/16/32, lanes 0..7 store a,b.
//   Block 0 zeroes Msum.
// Phase 2 (blocks 0..31): stage a,b chunk to LDS, 64x64 partial in regs
//   (8 rows/thread-group), atomicAdd into Msum (proven cheaper than
//   private-partial re-reduce).
// Phase 3 (blocks 0..15): csi[k] = (1/D) F[k] Msum F[k]^T, 64 k per block,
//   8 j-groups x 8 cols per thread, padded LDS, block reduce, store.
// ---------------------------------------------------------------------------
__global__ __launch_bounds__(512) void k_fused(const float* __restrict__ atten,
                                               const float* __restrict__ rad,
                                               const float* __restrict__ freq,
                                               float* __restrict__ ws,
                                               float* __restrict__ out) {
    const int t    = threadIdx.x;
    const int bid  = blockIdx.x;
    const int wave = t >> 6;
    const int lane = t & 63;

    // Phase-overlaid LDS pool: phase 2 uses 16 KiB, phase 3 ~36 KiB.
    __shared__ float smem[64 * 68 + 64 * 65 + 8 * 64]; // 9024 floats ~ 35.3 KiB

    // ---------------- Phase 1: p-reduction (all blocks) ----------------
    {
        const int d    = bid * 4 + (wave >> 1);
        const int half = wave & 1;
        const int r4g  = lane & 7;
        const int pr   = lane >> 3;

        if (bid == 0) { // zero Msum: 512 threads x 2 float4 = 4096 floats
            v4f z = {0.f, 0.f, 0.f, 0.f};
            ((v4f*)(ws + WS_MSUM))[t]       = z;
            ((v4f*)(ws + WS_MSUM))[t + 512] = z;
        }

        const int base = pr * 16 + half * 8 + r4g;
        const v4f* A4 = (const v4f*)atten + (size_t)d * 4096 + base;
        const v4f* B4 = (const v4f*)rad   + (size_t)d * 4096 + base;

        v4f pa[8], pb[8], na[8], nb[8];
#pragma unroll
        for (int j = 0; j < 8; ++j) pa[j] = ntload(A4 + j * 128);
#pragma unroll
        for (int j = 0; j < 8; ++j) pb[j] = ntload(B4 + j * 128);

        v4f acc_a = {0.f, 0.f, 0.f, 0.f};
        v4f acc_b = {0.f, 0.f, 0.f, 0.f};

#pragma unroll
        for (int mc = 0; mc < 4; ++mc) {
            if (mc < 3) {
                const int off = (mc + 1) * 8 * 128;
#pragma unroll
                for (int j = 0; j < 8; ++j) na[j] = ntload(A4 + off + j * 128);
#pragma unroll
                for (int j = 0; j < 8; ++j) nb[j] = ntload(B4 + off + j * 128);
            }
            acc_a = acc_a + (((pa[0] + pa[1]) + (pa[2] + pa[3])) +
                             ((pa[4] + pa[5]) + (pa[6] + pa[7])));
            acc_b = acc_b + (((pb[0] + pb[1]) + (pb[2] + pb[3])) +
                             ((pb[4] + pb[5]) + (pb[6] + pb[7])));
#pragma unroll
            for (int j = 0; j < 8; ++j) { pa[j] = na[j]; pb[j] = nb[j]; }
        }

        acc_a = acc_a + shfl_xor_v4(acc_a, 8);
        acc_a = acc_a + shfl_xor_v4(acc_a, 16);
        acc_a = acc_a + shfl_xor_v4(acc_a, 32);
        acc_b = acc_b + shfl_xor_v4(acc_b, 8);
        acc_b = acc_b + shfl_xor_v4(acc_b, 16);
        acc_b = acc_b + shfl_xor_v4(acc_b, 32);

        if (pr == 0) { // lanes 0..7
            ((v4f*)(ws + WS_A))[d * 16 + half * 8 + r4g] = acc_a;
            ((v4f*)(ws + WS_B))[d * 16 + half * 8 + r4g] = acc_b;
        }
    }

    cg::this_grid().sync();

    // ---------------- Phase 2: M accumulation (blocks 0..31) ----------------
    if (bid < NB_B) {
        float* sa = smem;                    // 2048 floats
        float* sb = smem + DCHUNK * R_RANK;  // 2048 floats

        const float4* a4 = (const float4*)(ws + WS_A) + bid * (DCHUNK * R_RANK / 4);
        const float4* b4 = (const float4*)(ws + WS_B) + bid * (DCHUNK * R_RANK / 4);
        ((float4*)sa)[t] = a4[t]; // 512 threads x 1 float4 = 512 float4
        ((float4*)sb)[t] = b4[t];
        __syncthreads();

        const int c  = t & 63;
        const int wg = t >> 6; // 0..7, 8 rows each

        float acc[8];
#pragma unroll
        for (int i = 0; i < 8; ++i) acc[i] = 0.f;

        for (int dd = 0; dd < DCHUNK; ++dd) {
            const float bv = sb[dd * 64 + c];
            const float4* ar = (const float4*)&sa[dd * 64 + wg * 8];
            const float4 a0 = ar[0], a1 = ar[1];
            acc[0] += a0.x * bv; acc[1] += a0.y * bv; acc[2] += a0.z * bv; acc[3] += a0.w * bv;
            acc[4] += a1.x * bv; acc[5] += a1.y * bv; acc[6] += a1.z * bv; acc[7] += a1.w * bv;
        }

        float* Msum = ws + WS_MSUM;
#pragma unroll
        for (int i = 0; i < 8; ++i)
            atomicAdd(&Msum[(wg * 8 + i) * 64 + c], acc[i]);
    }

    cg::this_grid().sync();

    // ---------------- Phase 3: csi (blocks 0..15) ----------------
    if (bid < 16) {
        float* Ms  = smem;                    // 64*68
        float* Fs  = smem + 64 * 68;          // 64*65
        float* red = smem + 64 * 68 + 64 * 65; // 8*64

        const float4* M4 = (const float4*)(ws + WS_MSUM);
#pragma unroll
        for (int i = 0; i < 2; ++i) {
            const int idx4 = i * 512 + t;
            const float4 s = M4[idx4];
            const int r = idx4 >> 4, c4 = idx4 & 15;
            *(float4*)&Ms[r * 68 + c4 * 4] = s;
        }

        const float4* F4 = (const float4*)freq + bid * 1024;
#pragma unroll
        for (int i = 0; i < 2; ++i) {
            const int idx4 = i * 512 + t;
            const float4 v = F4[idx4];
            const int row = idx4 >> 4, c4 = idx4 & 15;
            Fs[row * 65 + c4 * 4 + 0] = v.x;
            Fs[row * 65 + c4 * 4 + 1] = v.y;
            Fs[row * 65 + c4 * 4 + 2] = v.z;
            Fs[row * 65 + c4 * 4 + 3] = v.w;
        }
        __syncthreads();

        const int kl = t & 63;
        const int jg = t >> 6; // 0..7, 8 cols each

        float h[8];
#pragma unroll
        for (int j = 0; j < 8; ++j) h[j] = 0.f;

        for (int r = 0; r < 64; ++r) {
            const float fv = Fs[kl * 65 + r];
            const float4* mr = (const float4*)&Ms[r * 68 + jg * 8];
            const float4 m0 = mr[0], m1 = mr[1];
            h[0] += fv * m0.x; h[1] += fv * m0.y; h[2] += fv * m0.z; h[3] += fv * m0.w;
            h[4] += fv * m1.x; h[5] += fv * m1.y; h[6] += fv * m1.z; h[7] += fv * m1.w;
        }

        float part = 0.f;
#pragma unroll
        for (int j = 0; j < 8; ++j) part += h[j] * Fs[kl * 65 + jg * 8 + j];

        red[jg * 64 + kl] = part;
        __syncthreads();
        if (t < 64) {
            float s = 0.f;
#pragma unroll
            for (int g = 0; g < 8; ++g) s += red[g * 64 + t];
            out[bid * 64 + t] = s * (1.0f / (float)D_DIRS);
        }
    }
}

extern "C" void kernel_launch(void* const* d_in, const int* in_sizes, int n_in,
                              void* d_out, int out_size, void* d_ws, size_t ws_size,
                              hipStream_t stream) {
    const float* atten = (const float*)d_in[0]; // (D,P,R)
    const float* rad   = (const float*)d_in[1]; // (D,P,R)
    const float* freq  = (const float*)d_in[2]; // (K,R)
    float* out = (float*)d_out;                 // (K,)
    float* ws  = (float*)d_ws;                  // needs 528 KiB

    void* args[] = {(void*)&atten, (void*)&rad, (void*)&freq, (void*)&ws, (void*)&out};
    hipLaunchCooperativeKernel((const void*)k_fused, dim3(D_DIRS / 4), dim3(512),
                               args, 0, stream);
}